// Round 2
// baseline (93.771 us; speedup 1.0000x reference)
//
#include <hip/hip_runtime.h>

typedef unsigned int u32;
typedef u32 u32x4 __attribute__((ext_vector_type(4)));
typedef float f32x4 __attribute__((ext_vector_type(4)));

#define N_ROWS 2048
#define K_DIM  1024
#define O_DIM  4096

#define BN 128
#define BO 128
#define KC 128            // k-bytes staged per iteration
#define NKT (K_DIM / KC)  // 8
#define NTHR 256

#define QSCALE   23.090909f      // 127 / 5.5
#define QBIAS    128.5f          // +128 bias, +0.5 for round via trunc
#define INVSCALE (5.5f / 127.0f)

// v_sad_u8: D = sum_{i<4} |S0.byte[i] - S1.byte[i]| + S2
__device__ __forceinline__ u32 sad_u8(u32 a, u32 b, u32 c) {
  u32 d;
  asm("v_sad_u8 %0, %1, %2, %3" : "=v"(d) : "v"(a), "v"(b), "v"(c));
  return d;
}

__device__ __forceinline__ u32 quant4(f32x4 v) {
  u32 b0 = (u32)fminf(fmaxf(fmaf(v[0], QSCALE, QBIAS), 0.f), 255.f);
  u32 b1 = (u32)fminf(fmaxf(fmaf(v[1], QSCALE, QBIAS), 0.f), 255.f);
  u32 b2 = (u32)fminf(fmaxf(fmaf(v[2], QSCALE, QBIAS), 0.f), 255.f);
  u32 b3 = (u32)fminf(fmaxf(fmaf(v[3], QSCALE, QBIAS), 0.f), 255.f);
  return b0 | (b1 << 8) | (b2 << 16) | (b3 << 24);
}

__global__ void quant_kernel(const float* __restrict__ src, u32* __restrict__ dst, int n4) {
  int i = blockIdx.x * blockDim.x + threadIdx.x;
  if (i < n4) {
    f32x4 v = ((const f32x4*)src)[i];
    dst[i] = quant4(v);
  }
}

// LDS layout (per buffer, per operand): plain [chunk(8)][row(128)][16B] = 16 KB.
// Reads use two base regs (ty*16 / tx*16) + compile-time immediates only.
// x-reads: 16-lane broadcast, 4 consecutive-row addrs -> conflict-free.
// w-reads: 16 stride-16B addrs -> 2-way (free, m136).
// staging writes: lane -> consecutive rows -> conflict-free.
template <bool U8SRC>
__global__ __launch_bounds__(NTHR, 2)
void l1_main(const void* __restrict__ xsrc, const void* __restrict__ wsrc,
             const float* __restrict__ bias, float* __restrict__ out) {
  __shared__ __align__(16) unsigned char lds[2 * 32768];  // [buf][x 16K | w 16K]

  const int tid = threadIdx.x;
  const int tx = tid & 15;   // o = j*16 + tx
  const int ty = tid >> 4;   // n = i*16 + ty   (ty: 0..15)
  const int bo = blockIdx.x & 31;
  const int bn = blockIdx.x >> 5;
  const int n0 = bn * BN, o0 = bo * BO;

  const int srow = tid & 127;  // staging row
  const int scb = tid >> 7;    // staging chunk base (0/1); chunk = scb + 2p

  u32x4 xr[4], wr[4];  // in-flight staging registers

  u32 acc[8][8];
#pragma unroll
  for (int i = 0; i < 8; ++i)
#pragma unroll
    for (int j = 0; j < 8; ++j) acc[i][j] = 0;

  auto load_tile = [&](int kt) {
    if constexpr (U8SRC) {
      const unsigned char* gx = (const unsigned char*)xsrc +
                                (size_t)(n0 + srow) * K_DIM + kt * KC + scb * 16;
      const unsigned char* gw = (const unsigned char*)wsrc +
                                (size_t)(o0 + srow) * K_DIM + kt * KC + scb * 16;
#pragma unroll
      for (int p = 0; p < 4; ++p) {
        xr[p] = *(const u32x4*)(gx + p * 32);
        wr[p] = *(const u32x4*)(gw + p * 32);
      }
    } else {
      const float* gx = (const float*)xsrc + (size_t)(n0 + srow) * K_DIM + kt * KC + scb * 16;
      const float* gw = (const float*)wsrc + (size_t)(o0 + srow) * K_DIM + kt * KC + scb * 16;
#pragma unroll
      for (int p = 0; p < 4; ++p)
#pragma unroll
        for (int q = 0; q < 4; ++q) {
          xr[p][q] = quant4(*(const f32x4*)(gx + p * 32 + q * 4));
          wr[p][q] = quant4(*(const f32x4*)(gw + p * 32 + q * 4));
        }
    }
  };

  auto write_tile = [&](int p) {
    unsigned char* xl = lds + p * 32768 + scb * 2048 + srow * 16;
    unsigned char* wl = xl + 16384;
#pragma unroll
    for (int q = 0; q < 4; ++q) {   // chunk = scb + 2q -> +q*4096
      *(u32x4*)(xl + q * 4096) = xr[q];
      *(u32x4*)(wl + q * 4096) = wr[q];
    }
  };

  auto compute = [&](int p) {
    const unsigned char* xb = lds + p * 32768 + ty * 16;
    const unsigned char* wb = lds + p * 32768 + 16384 + tx * 16;
#pragma unroll
    for (int c = 0; c < 8; ++c) {
      u32x4 xv[8], wv[8];
#pragma unroll
      for (int i = 0; i < 8; ++i) xv[i] = *(const u32x4*)(xb + c * 2048 + i * 256);
#pragma unroll
      for (int j = 0; j < 8; ++j) wv[j] = *(const u32x4*)(wb + c * 2048 + j * 256);
#pragma unroll
      for (int i = 0; i < 8; ++i)
#pragma unroll
        for (int j = 0; j < 8; ++j) {
          acc[i][j] = sad_u8(xv[i][0], wv[j][0], acc[i][j]);
          acc[i][j] = sad_u8(xv[i][1], wv[j][1], acc[i][j]);
          acc[i][j] = sad_u8(xv[i][2], wv[j][2], acc[i][j]);
          acc[i][j] = sad_u8(xv[i][3], wv[j][3], acc[i][j]);
        }
    }
  };

  load_tile(0);
  write_tile(0);
  __syncthreads();

#pragma unroll 1
  for (int kt = 0; kt < NKT; ++kt) {
    if (kt + 1 < NKT) load_tile(kt + 1);  // issue early: latency hides under sads
    compute(kt & 1);
    __syncthreads();                       // everyone done reading buf (kt&1)... 
    if (kt + 1 < NKT) {
      write_tile((kt + 1) & 1);            // ...and done reading buf (kt+1)&1 since kt-1
      __syncthreads();
    }
  }

  // epilogue: out = bias - acc * (1/scale)
  float bj[8];
#pragma unroll
  for (int j = 0; j < 8; ++j) bj[j] = bias[o0 + j * 16 + tx];
#pragma unroll
  for (int i = 0; i < 8; ++i) {
    float* orow = out + (size_t)(n0 + i * 16 + ty) * O_DIM + o0 + tx;
#pragma unroll
    for (int j = 0; j < 8; ++j)
      orow[j * 16] = fmaf((float)acc[i][j], -INVSCALE, bj[j]);
  }
}

extern "C" void kernel_launch(void* const* d_in, const int* in_sizes, int n_in,
                              void* d_out, int out_size, void* d_ws, size_t ws_size,
                              hipStream_t stream) {
  const float* x = (const float*)d_in[0];     // (2,1024,1024) f32
  const float* w = (const float*)d_in[1];     // (4096,1024) f32
  const float* bias = (const float*)d_in[2];  // (4096,) f32
  float* out = (float*)d_out;                 // (2,1024,4096) f32

  const size_t qx_bytes = (size_t)N_ROWS * K_DIM;  // 2 MB
  const size_t qw_bytes = (size_t)O_DIM * K_DIM;   // 4 MB

  dim3 grid((N_ROWS / BN) * (O_DIM / BO));  // 16 * 32 = 512
  dim3 block(NTHR);

  if (ws_size >= qx_bytes + qw_bytes) {
    u32* qx = (u32*)d_ws;
    u32* qw = (u32*)((char*)d_ws + qx_bytes);
    int n4x = (int)(qx_bytes / 4);
    int n4w = (int)(qw_bytes / 4);
    quant_kernel<<<(n4x + 255) / 256, 256, 0, stream>>>(x, qx, n4x);
    quant_kernel<<<(n4w + 255) / 256, 256, 0, stream>>>(w, qw, n4w);
    l1_main<true><<<grid, block, 0, stream>>>(qx, qw, bias, out);
  } else {
    l1_main<false><<<grid, block, 0, stream>>>(x, w, bias, out);
  }
}